// Round 2
// baseline (217.978 us; speedup 1.0000x reference)
//
#include <hip/hip_runtime.h>

#define NB 64
#define NT 2048
#define NQD 512
#define NKD 512
#define NVD 512
#define NAD 256

typedef __attribute__((ext_vector_type(8))) short s16x8;
typedef __attribute__((ext_vector_type(4))) float fx4;

__device__ __forceinline__ short f2bf(float x) {
  union { float f; unsigned u; } v; v.f = x;
  return (short)((v.u + 0x7fffu + ((v.u >> 16) & 1u)) >> 16);  // RNE
}

// tanh(x) = 1 - 2/(1+e^{2x});  exact saturation at +/-1, rel err ~1e-7
__device__ __forceinline__ float fast_tanh(float x) {
  float e = __expf(x + x);
  return 1.0f - 2.0f * __builtin_amdgcn_rcpf(e + 1.0f);
}

__device__ __forceinline__ void gload_lds16(const void* g, void* l) {
  __builtin_amdgcn_global_load_lds(
      (const __attribute__((address_space(1))) unsigned int*)g,
      (__attribute__((address_space(3))) unsigned int*)l, 16, 0, 0);
}

// ---- kernel 1: fused prep.  blocks 0..63: qpk[b][n] = query[b]·Wq[:,n]+bq+bk
//                             blocks 64..95: WkT[a][k] = bf16(Wk[k][a])
__global__ void prep_kernel(const float* __restrict__ query, const float* __restrict__ Wq,
                            const float* __restrict__ bq, const float* __restrict__ bk,
                            const float* __restrict__ Wk,
                            float* __restrict__ qpk, short* __restrict__ WkT) {
  __shared__ float sm[64][65];
  const int tid = threadIdx.x;
  if (blockIdx.x < NB) {
    const int b = blockIdx.x;
    float* q = &sm[0][0];
    for (int k = tid; k < NQD; k += 256) q[k] = query[b * NQD + k];
    __syncthreads();
    float acc = bq[tid] + bk[tid];
#pragma unroll 8
    for (int k = 0; k < NQD; ++k) acc += q[k] * Wq[k * NAD + tid];
    qpk[b * NAD + tid] = acc;
  } else {
    const int blk = blockIdx.x - NB;
    const int kb = (blk & 7) * 64, ab = (blk >> 3) * 64;
    const int c = tid & 63, r0 = tid >> 6;
#pragma unroll
    for (int rr = r0; rr < 64; rr += 4)
      sm[rr][c] = Wk[(size_t)(kb + rr) * NAD + ab + c];
    __syncthreads();
#pragma unroll
    for (int rr = r0; rr < 64; rr += 4)
      WkT[(size_t)(ab + rr) * NKD + kb + c] = f2bf(sm[c][rr]);
  }
}

// ---- kernel 2: fused GEMM(key@Wk) + tanh + ·Wo reduce -> score[b*T+t]
// BM=128 rows, BN=256 (full AD, 64 n/wave), BK=32, double-buffered, 1 barrier/K-step.
__global__ void __launch_bounds__(256)
score_kernel(const float* __restrict__ key, const short* __restrict__ WkT,
             const float* __restrict__ qpk, const float* __restrict__ Wo,
             float* __restrict__ score) {
  __shared__ short As[2][128 * 32];   // 2 x 8 KB
  __shared__ short Bs[2][256 * 32];   // 2 x 16 KB
  __shared__ float sred[4][128];      // 2 KB
  const int tid = threadIdx.x;
  const int w = tid >> 6, l = tid & 63;
  const int g = l >> 4, h = l & 15;
  const int m0 = blockIdx.x * 128;    // 16 blocks per batch; tiles never span batches
  const int b = m0 >> 11;

  float qv[4], wv[4];
#pragma unroll
  for (int nt = 0; nt < 4; ++nt) {
    const int n = w * 64 + nt * 16 + h;
    qv[nt] = qpk[b * NAD + n];
    wv[nt] = Wo[n];
  }

  fx4 acc[8][4];
#pragma unroll
  for (int i = 0; i < 8; ++i)
#pragma unroll
    for (int j = 0; j < 4; ++j) acc[i][j] = fx4{0.f, 0.f, 0.f, 0.f};

  const int ar = tid >> 1;            // A stage: row 0..127
  const int ak = (tid & 1) * 16;      // A stage: 16 consecutive k per thread
  const float* arow = key + (size_t)(m0 + ar) * NKD + ak;

  // prologue: stage K-step 0 into buf 0
  {
    fx4 a0 = *(const fx4*)(arow + 0), a1 = *(const fx4*)(arow + 4);
    fx4 a2 = *(const fx4*)(arow + 8), a3 = *(const fx4*)(arow + 12);
    s16x8 v0, v1;
    v0[0]=f2bf(a0[0]); v0[1]=f2bf(a0[1]); v0[2]=f2bf(a0[2]); v0[3]=f2bf(a0[3]);
    v0[4]=f2bf(a1[0]); v0[5]=f2bf(a1[1]); v0[6]=f2bf(a1[2]); v0[7]=f2bf(a1[3]);
    v1[0]=f2bf(a2[0]); v1[1]=f2bf(a2[1]); v1[2]=f2bf(a2[2]); v1[3]=f2bf(a2[3]);
    v1[4]=f2bf(a3[0]); v1[5]=f2bf(a3[1]); v1[6]=f2bf(a3[2]); v1[7]=f2bf(a3[3]);
    *(s16x8*)(&As[0][ar * 32 + ak]) = v0;
    *(s16x8*)(&As[0][ar * 32 + ak + 8]) = v1;
#pragma unroll
    for (int i = 0; i < 4; ++i) {
      const int c = tid + i * 256;
      gload_lds16(WkT + (size_t)(c >> 2) * NKD + (c & 3) * 8, &Bs[0][c * 8]);
    }
  }
  __syncthreads();

  int buf = 0;
  for (int ks = 0; ks < 16; ++ks) {
    fx4 a0, a1, a2, a3;
    const bool hasNext = (ks < 15);
    if (hasNext) {
      // T14 issue-early: A loads to regs + B direct-to-LDS for tile ks+1
      const float* gp = arow + (ks + 1) * 32;
      a0 = *(const fx4*)(gp + 0);  a1 = *(const fx4*)(gp + 4);
      a2 = *(const fx4*)(gp + 8);  a3 = *(const fx4*)(gp + 12);
#pragma unroll
      for (int i = 0; i < 4; ++i) {
        const int c = tid + i * 256;
        gload_lds16(WkT + (size_t)(c >> 2) * NKD + (ks + 1) * 32 + (c & 3) * 8,
                    &Bs[buf ^ 1][c * 8]);
      }
    }
    // fragments from current buffer
    s16x8 af[8], bfr[4];
#pragma unroll
    for (int mt = 0; mt < 8; ++mt)
      af[mt] = *(const s16x8*)(&As[buf][(mt * 16 + h) * 32 + g * 8]);
#pragma unroll
    for (int nt = 0; nt < 4; ++nt)
      bfr[nt] = *(const s16x8*)(&Bs[buf][(w * 64 + nt * 16 + h) * 32 + g * 8]);
#pragma unroll
    for (int mt = 0; mt < 8; ++mt)
#pragma unroll
      for (int nt = 0; nt < 4; ++nt)
        acc[mt][nt] = __builtin_amdgcn_mfma_f32_16x16x32_bf16(af[mt], bfr[nt], acc[mt][nt], 0, 0, 0);
    if (hasNext) {
      // T14 write-late: convert + LDS-write A after the MFMAs
      s16x8 v0, v1;
      v0[0]=f2bf(a0[0]); v0[1]=f2bf(a0[1]); v0[2]=f2bf(a0[2]); v0[3]=f2bf(a0[3]);
      v0[4]=f2bf(a1[0]); v0[5]=f2bf(a1[1]); v0[6]=f2bf(a1[2]); v0[7]=f2bf(a1[3]);
      v1[0]=f2bf(a2[0]); v1[1]=f2bf(a2[1]); v1[2]=f2bf(a2[2]); v1[3]=f2bf(a2[3]);
      v1[4]=f2bf(a3[0]); v1[5]=f2bf(a3[1]); v1[6]=f2bf(a3[2]); v1[7]=f2bf(a3[3]);
      *(s16x8*)(&As[buf ^ 1][ar * 32 + ak]) = v0;
      *(s16x8*)(&As[buf ^ 1][ar * 32 + ak + 8]) = v1;
    }
    __syncthreads();
    buf ^= 1;
  }

  // epilogue: score row m = m0 + mt*16 + 4g + r  (C layout col=h, row=4g+reg)
#pragma unroll
  for (int mt = 0; mt < 8; ++mt) {
#pragma unroll
    for (int r = 0; r < 4; ++r) {
      float s = fast_tanh(acc[mt][0][r] + qv[0]) * wv[0]
              + fast_tanh(acc[mt][1][r] + qv[1]) * wv[1]
              + fast_tanh(acc[mt][2][r] + qv[2]) * wv[2]
              + fast_tanh(acc[mt][3][r] + qv[3]) * wv[3];
#pragma unroll
      for (int off = 1; off < 16; off <<= 1) s += __shfl_xor(s, off, 64);
      if (h == 0) sred[w][mt * 16 + g * 4 + r] = s;
    }
  }
  __syncthreads();
  if (tid < 128)
    score[m0 + tid] = sred[0][tid] + sred[1][tid] + sred[2][tid] + sred[3][tid];
}

// ---- kernel 3: softmax over T per batch (bo dropped: softmax shift-invariant)
__global__ void softmax_kernel(const float* __restrict__ score, float* __restrict__ attn) {
  __shared__ float redm[4];
  __shared__ float reds[4];
  const int b = blockIdx.x, tid = threadIdx.x;
  const float* s = score + (size_t)b * NT;
  float v[8];
  float m = -3.0e38f;
#pragma unroll
  for (int j = 0; j < 8; ++j) { v[j] = s[tid + j * 256]; m = fmaxf(m, v[j]); }
#pragma unroll
  for (int off = 1; off < 64; off <<= 1) m = fmaxf(m, __shfl_xor(m, off, 64));
  if ((tid & 63) == 0) redm[tid >> 6] = m;
  __syncthreads();
  m = fmaxf(fmaxf(redm[0], redm[1]), fmaxf(redm[2], redm[3]));
  float sum = 0.f;
#pragma unroll
  for (int j = 0; j < 8; ++j) { v[j] = __expf(v[j] - m); sum += v[j]; }
#pragma unroll
  for (int off = 1; off < 64; off <<= 1) sum += __shfl_xor(sum, off, 64);
  if ((tid & 63) == 0) reds[tid >> 6] = sum;
  __syncthreads();
  sum = reds[0] + reds[1] + reds[2] + reds[3];
  const float inv = 1.0f / sum;
#pragma unroll
  for (int j = 0; j < 8; ++j) attn[(size_t)b * NT + tid + j * 256] = v[j] * inv;
}

// ---- kernel 4: partial context over 64-row t-chunks (float4 loads)
__global__ void ctx_partial_kernel(const float* __restrict__ attn, const float* __restrict__ value,
                                   float* __restrict__ partial) {
  __shared__ float a[64];
  __shared__ fx4 red[128];
  const int blk = blockIdx.x;       // b*32 + tc
  const int b = blk >> 5, tc = blk & 31;
  const int tid = threadIdx.x;
  if (tid < 64) a[tid] = attn[(size_t)b * NT + tc * 64 + tid];
  __syncthreads();
  const int half = tid >> 7;        // 0: even rows, 1: odd rows
  const int vi = (tid & 127) * 4;   // 128 threads cover VD=512
  const float* vp = value + ((size_t)b * NT + tc * 64 + half) * NVD + vi;
  fx4 s = fx4{0.f, 0.f, 0.f, 0.f};
#pragma unroll 8
  for (int t = 0; t < 64; t += 2) {
    fx4 x = *(const fx4*)(vp + (size_t)t * NVD);
    const float wt = a[t + half];
    s += x * wt;
  }
  if (half) red[tid & 127] = s;
  __syncthreads();
  if (!half) {
    s += red[tid];
    *(fx4*)(partial + (size_t)blk * NVD + vi) = s;
  }
}

// ---- kernel 5: reduce partials -> context
__global__ void ctx_reduce_kernel(const float* __restrict__ partial, float* __restrict__ ctx) {
  const int i = blockIdx.x * 256 + threadIdx.x;  // < NB*NVD
  const int b = i >> 9, v = i & (NVD - 1);
  float s = 0.f;
#pragma unroll
  for (int tc = 0; tc < 32; ++tc) s += partial[(size_t)(b * 32 + tc) * NVD + v];
  ctx[i] = s;
}

extern "C" void kernel_launch(void* const* d_in, const int* in_sizes, int n_in,
                              void* d_out, int out_size, void* d_ws, size_t ws_size,
                              hipStream_t stream) {
  const float* query = (const float*)d_in[0];
  const float* key   = (const float*)d_in[1];
  const float* value = (const float*)d_in[2];
  const float* Wq    = (const float*)d_in[3];
  const float* bq    = (const float*)d_in[4];
  const float* Wk    = (const float*)d_in[5];
  const float* bk    = (const float*)d_in[6];
  const float* Wo    = (const float*)d_in[7];
  // d_in[8] = bo: unused — softmax over T is invariant to a uniform shift.

  float* out  = (float*)d_out;
  float* ctx  = out;                // [B][VD]
  float* attn = out + NB * NVD;     // [B][T]

  char* ws = (char*)d_ws;
  float* qpk     = (float*)(ws);                                   // 64 KB
  short* WkT     = (short*)(ws + 64 * 1024);                       // 256 KB
  float* score   = (float*)(ws + (64 + 256) * 1024);               // 512 KB
  float* partial = (float*)(ws + (64 + 256 + 512) * 1024);         // 4 MB

  prep_kernel<<<NB + 32, 256, 0, stream>>>(query, Wq, bq, bk, Wk, qpk, WkT);
  score_kernel<<<(NB * NT) / 128, 256, 0, stream>>>(key, WkT, qpk, Wo, score);
  softmax_kernel<<<NB, 256, 0, stream>>>(score, attn);
  ctx_partial_kernel<<<NB * 32, 256, 0, stream>>>(attn, value, partial);
  ctx_reduce_kernel<<<(NB * NVD) / 256, 256, 0, stream>>>(partial, ctx);
}

// Round 3
// 186.020 us; speedup vs baseline: 1.1718x; 1.1718x over previous
//
#include <hip/hip_runtime.h>

#define NB 64
#define NT 2048
#define NQD 512
#define NKD 512
#define NVD 512
#define NAD 256

typedef __attribute__((ext_vector_type(8))) short s16x8;
typedef __attribute__((ext_vector_type(4))) float fx4;

__device__ __forceinline__ short f2bf(float x) {
  union { float f; unsigned u; } v; v.f = x;
  return (short)((v.u + 0x7fffu + ((v.u >> 16) & 1u)) >> 16);  // RNE
}

// tanh(x) = 1 - 2/(1+e^{2x});  exact saturation at +/-1, rel err ~1e-7
__device__ __forceinline__ float fast_tanh(float x) {
  float e = __expf(x + x);
  return 1.0f - 2.0f * __builtin_amdgcn_rcpf(e + 1.0f);
}

// ---- kernel 1: fused prep.  blocks 0..63: qpk[b][n] = query[b]·Wq[:,n]+bq+bk
//                             blocks 64..95: WkT[a][k] = bf16(Wk[k][a])
__global__ void prep_kernel(const float* __restrict__ query, const float* __restrict__ Wq,
                            const float* __restrict__ bq, const float* __restrict__ bk,
                            const float* __restrict__ Wk,
                            float* __restrict__ qpk, short* __restrict__ WkT) {
  __shared__ float sm[64][65];
  const int tid = threadIdx.x;
  if (blockIdx.x < NB) {
    const int b = blockIdx.x;
    float* q = &sm[0][0];
    for (int k = tid; k < NQD; k += 256) q[k] = query[b * NQD + k];
    __syncthreads();
    float acc = bq[tid] + bk[tid];
#pragma unroll 8
    for (int k = 0; k < NQD; ++k) acc += q[k] * Wq[k * NAD + tid];
    qpk[b * NAD + tid] = acc;
  } else {
    const int blk = blockIdx.x - NB;
    const int kb = (blk & 7) * 64, ab = (blk >> 3) * 64;
    const int c = tid & 63, r0 = tid >> 6;
#pragma unroll
    for (int rr = r0; rr < 64; rr += 4)
      sm[rr][c] = Wk[(size_t)(kb + rr) * NAD + ab + c];
    __syncthreads();
#pragma unroll
    for (int rr = r0; rr < 64; rr += 4)
      WkT[(size_t)(ab + rr) * NKD + kb + c] = f2bf(sm[c][rr]);
  }
}

// ---- kernel 2: fused GEMM(key@Wk) + tanh + ·Wo reduce -> score[b*T+t]
// BM=64, BN=256 (64 n/wave), BK=32. A in LDS (k-group-major, swizzled, dbuf);
// B fragments straight from L2-resident WkT, reg-double-buffered.
__global__ void __launch_bounds__(256, 3)
score_kernel(const float* __restrict__ key, const short* __restrict__ WkT,
             const float* __restrict__ qpk, const float* __restrict__ Wo,
             float* __restrict__ score) {
  // As[buf]: 256 entries of 16B; entry (g,row) at short-index ((g*64+row)*8)^(g<<3)
  __shared__ short As[2][4 * 64 * 8];   // 2 x 4 KB
  __shared__ float sred[4][64];
  const int tid = threadIdx.x;
  const int w = tid >> 6, l = tid & 63;
  const int g = l >> 4, h = l & 15;
  const int m0 = blockIdx.x * 64;       // 32 blocks/batch; tiles never span batches
  const int b = m0 >> 11;

  float qv[4], wv[4];
  const short* bp[4];
#pragma unroll
  for (int nt = 0; nt < 4; ++nt) {
    const int n = w * 64 + nt * 16 + h;
    qv[nt] = qpk[b * NAD + n];
    wv[nt] = Wo[n];
    bp[nt] = WkT + (size_t)n * NKD + g * 8;
  }

  fx4 acc[4][4];
#pragma unroll
  for (int i = 0; i < 4; ++i)
#pragma unroll
    for (int j = 0; j < 4; ++j) acc[i][j] = fx4{0.f, 0.f, 0.f, 0.f};

  // staging role: 4 lanes per row -> 128B contiguous per row per K-step
  const int srow = tid >> 2, sg = tid & 3;
  const float* asrc = key + (size_t)(m0 + srow) * NKD + sg * 8;
  const int sidx = ((sg * 64 + srow) * 8) ^ (sg << 3);  // swizzled LDS short-index

  s16x8 bcur[4];
  // prologue: stage K-step 0 + load B frags for K-step 0
  {
    fx4 a0 = *(const fx4*)asrc;
    fx4 a1 = *(const fx4*)(asrc + 4);
    s16x8 v;
    v[0]=f2bf(a0[0]); v[1]=f2bf(a0[1]); v[2]=f2bf(a0[2]); v[3]=f2bf(a0[3]);
    v[4]=f2bf(a1[0]); v[5]=f2bf(a1[1]); v[6]=f2bf(a1[2]); v[7]=f2bf(a1[3]);
    *(s16x8*)&As[0][sidx] = v;
#pragma unroll
    for (int nt = 0; nt < 4; ++nt) bcur[nt] = *(const s16x8*)bp[nt];
  }
  __syncthreads();

  int buf = 0;
#pragma unroll 2
  for (int ks = 0; ks < 16; ++ks) {
    const bool hasNext = (ks < 15);
    fx4 a0, a1;
    s16x8 bnxt[4];
    if (hasNext) {
      const float* gp = asrc + (ks + 1) * 32;
      a0 = *(const fx4*)gp;
      a1 = *(const fx4*)(gp + 4);
#pragma unroll
      for (int nt = 0; nt < 4; ++nt)
        bnxt[nt] = *(const s16x8*)(bp[nt] + (ks + 1) * 32);
    }
    s16x8 af[4];
#pragma unroll
    for (int mt = 0; mt < 4; ++mt)
      af[mt] = *(const s16x8*)&As[buf][((g * 64 + mt * 16 + h) * 8) ^ (g << 3)];
#pragma unroll
    for (int mt = 0; mt < 4; ++mt)
#pragma unroll
      for (int nt = 0; nt < 4; ++nt)
        acc[mt][nt] = __builtin_amdgcn_mfma_f32_16x16x32_bf16(af[mt], bcur[nt], acc[mt][nt], 0, 0, 0);
    if (hasNext) {
      s16x8 v;
      v[0]=f2bf(a0[0]); v[1]=f2bf(a0[1]); v[2]=f2bf(a0[2]); v[3]=f2bf(a0[3]);
      v[4]=f2bf(a1[0]); v[5]=f2bf(a1[1]); v[6]=f2bf(a1[2]); v[7]=f2bf(a1[3]);
      *(s16x8*)&As[buf ^ 1][sidx] = v;
#pragma unroll
      for (int nt = 0; nt < 4; ++nt) bcur[nt] = bnxt[nt];
    }
    __syncthreads();
    buf ^= 1;
  }

  // epilogue: score row m = m0 + mt*16 + 4g + r  (C layout col=h, row=4g+reg)
#pragma unroll
  for (int mt = 0; mt < 4; ++mt) {
#pragma unroll
    for (int r = 0; r < 4; ++r) {
      float s = fast_tanh(acc[mt][0][r] + qv[0]) * wv[0]
              + fast_tanh(acc[mt][1][r] + qv[1]) * wv[1]
              + fast_tanh(acc[mt][2][r] + qv[2]) * wv[2]
              + fast_tanh(acc[mt][3][r] + qv[3]) * wv[3];
#pragma unroll
      for (int off = 1; off < 16; off <<= 1) s += __shfl_xor(s, off, 64);
      if (h == 0) sred[w][mt * 16 + g * 4 + r] = s;
    }
  }
  __syncthreads();
  if (tid < 64)
    score[m0 + tid] = sred[0][tid] + sred[1][tid] + sred[2][tid] + sred[3][tid];
}

// ---- kernel 3: softmax over T per batch (bo dropped: softmax shift-invariant)
__global__ void softmax_kernel(const float* __restrict__ score, float* __restrict__ attn) {
  __shared__ float redm[4];
  __shared__ float reds[4];
  const int b = blockIdx.x, tid = threadIdx.x;
  const float* s = score + (size_t)b * NT;
  float v[8];
  float m = -3.0e38f;
#pragma unroll
  for (int j = 0; j < 8; ++j) { v[j] = s[tid + j * 256]; m = fmaxf(m, v[j]); }
#pragma unroll
  for (int off = 1; off < 64; off <<= 1) m = fmaxf(m, __shfl_xor(m, off, 64));
  if ((tid & 63) == 0) redm[tid >> 6] = m;
  __syncthreads();
  m = fmaxf(fmaxf(redm[0], redm[1]), fmaxf(redm[2], redm[3]));
  float sum = 0.f;
#pragma unroll
  for (int j = 0; j < 8; ++j) { v[j] = __expf(v[j] - m); sum += v[j]; }
#pragma unroll
  for (int off = 1; off < 64; off <<= 1) sum += __shfl_xor(sum, off, 64);
  if ((tid & 63) == 0) reds[tid >> 6] = sum;
  __syncthreads();
  sum = reds[0] + reds[1] + reds[2] + reds[3];
  const float inv = 1.0f / sum;
#pragma unroll
  for (int j = 0; j < 8; ++j) attn[(size_t)b * NT + tid + j * 256] = v[j] * inv;
}

// ---- kernel 4: partial context over 64-row t-chunks (float4 loads)
__global__ void ctx_partial_kernel(const float* __restrict__ attn, const float* __restrict__ value,
                                   float* __restrict__ partial) {
  __shared__ float a[64];
  __shared__ fx4 red[128];
  const int blk = blockIdx.x;       // b*32 + tc
  const int b = blk >> 5, tc = blk & 31;
  const int tid = threadIdx.x;
  if (tid < 64) a[tid] = attn[(size_t)b * NT + tc * 64 + tid];
  __syncthreads();
  const int half = tid >> 7;        // 0: even rows, 1: odd rows
  const int vi = (tid & 127) * 4;   // 128 threads cover VD=512
  const float* vp = value + ((size_t)b * NT + tc * 64 + half) * NVD + vi;
  fx4 s = fx4{0.f, 0.f, 0.f, 0.f};
#pragma unroll 8
  for (int t = 0; t < 64; t += 2) {
    fx4 x = *(const fx4*)(vp + (size_t)t * NVD);
    const float wt = a[t + half];
    s += x * wt;
  }
  if (half) red[tid & 127] = s;
  __syncthreads();
  if (!half) {
    s += red[tid];
    *(fx4*)(partial + (size_t)blk * NVD + vi) = s;
  }
}

// ---- kernel 5: reduce partials -> context
__global__ void ctx_reduce_kernel(const float* __restrict__ partial, float* __restrict__ ctx) {
  const int i = blockIdx.x * 256 + threadIdx.x;  // < NB*NVD
  const int b = i >> 9, v = i & (NVD - 1);
  float s = 0.f;
#pragma unroll
  for (int tc = 0; tc < 32; ++tc) s += partial[(size_t)(b * 32 + tc) * NVD + v];
  ctx[i] = s;
}

extern "C" void kernel_launch(void* const* d_in, const int* in_sizes, int n_in,
                              void* d_out, int out_size, void* d_ws, size_t ws_size,
                              hipStream_t stream) {
  const float* query = (const float*)d_in[0];
  const float* key   = (const float*)d_in[1];
  const float* value = (const float*)d_in[2];
  const float* Wq    = (const float*)d_in[3];
  const float* bq    = (const float*)d_in[4];
  const float* Wk    = (const float*)d_in[5];
  const float* bk    = (const float*)d_in[6];
  const float* Wo    = (const float*)d_in[7];
  // d_in[8] = bo: unused — softmax over T is invariant to a uniform shift.

  float* out  = (float*)d_out;
  float* ctx  = out;                // [B][VD]
  float* attn = out + NB * NVD;     // [B][T]

  char* ws = (char*)d_ws;
  float* qpk     = (float*)(ws);                                   // 64 KB
  short* WkT     = (short*)(ws + 64 * 1024);                       // 256 KB
  float* score   = (float*)(ws + (64 + 256) * 1024);               // 512 KB
  float* partial = (float*)(ws + (64 + 256 + 512) * 1024);         // 4 MB

  prep_kernel<<<NB + 32, 256, 0, stream>>>(query, Wq, bq, bk, Wk, qpk, WkT);
  score_kernel<<<(NB * NT) / 64, 256, 0, stream>>>(key, WkT, qpk, Wo, score);
  softmax_kernel<<<NB, 256, 0, stream>>>(score, attn);
  ctx_partial_kernel<<<NB * 32, 256, 0, stream>>>(attn, value, partial);
  ctx_reduce_kernel<<<(NB * NVD) / 256, 256, 0, stream>>>(partial, ctx);
}